// Round 7
// baseline (120.480 us; speedup 1.0000x reference)
//
#include <hip/hip_runtime.h>
#include <math.h>

#define N 4096
#define D 128
#define TS 64                      // output tile per 256-thread block
#define NT (N / TS)                // 64 tile rows
#define NBLK (NT * (NT + 1) / 2)   // 2080 lower-triangle tile pairs
#define NG (N / 16)                // 256 row groups of 16
#define TPAD 68                    // tgt LDS row stride (floats)

typedef __attribute__((ext_vector_type(8))) short short8;  // 8 x bf16
typedef __attribute__((ext_vector_type(4))) float f32x4;

union frag_u { short8 v; unsigned int u[4]; };

__device__ __forceinline__ unsigned int pack_bf16x2(float a, float b) {
    unsigned int ua = __float_as_uint(a), ub = __float_as_uint(b);
    ua = (ua + 0x7FFFu + ((ua >> 16) & 1u)) >> 16;
    ub = (ub + 0x7FFFu + ((ub >> 16) & 1u)) >> 16;
    return ua | (ub << 16);
}

// Kernel 1: repack O into MFMA-fragment order + compute s[i]=sqrt(1+||o_i||^2).
__global__ __launch_bounds__(256)
void prep_kernel(const float* __restrict__ O,
                 short8* __restrict__ Ofrag,
                 float* __restrict__ s) {
    __shared__ float psum[16][17];
    const int g    = blockIdx.x;          // 16-row group
    const int tid  = threadIdx.x;
    const int kk   = tid >> 6;            // 0..3 (wave = K-chunk)
    const int lane = tid & 63;
    const int r16  = lane & 15;
    const int qd   = lane >> 4;           // 0..3
    const float* src = O + (size_t)(g * 16 + r16) * D + kk * 32 + qd * 8;
    const float4 v0 = *(const float4*)(src);
    const float4 v1 = *(const float4*)(src + 4);
    frag_u f;
    f.u[0] = pack_bf16x2(v0.x, v0.y);
    f.u[1] = pack_bf16x2(v0.z, v0.w);
    f.u[2] = pack_bf16x2(v1.x, v1.y);
    f.u[3] = pack_bf16x2(v1.z, v1.w);
    Ofrag[(g * 4 + kk) * 64 + lane] = f.v;
    psum[kk * 4 + qd][r16] = v0.x * v0.x + v0.y * v0.y + v0.z * v0.z + v0.w * v0.w
                           + v1.x * v1.x + v1.y * v1.y + v1.z * v1.z + v1.w * v1.w;
    __syncthreads();
    if (tid < 16) {
        float acc = 1.0f;
        #pragma unroll
        for (int x = 0; x < 16; x++) acc += psum[x][tid];
        s[g * 16 + tid] = sqrtf(acc);
    }
}

__device__ __forceinline__ float acosh_dist(float B) {
    // clamp branch |B-1|<1e-6 -> 0 (inert here: B >= ~100 for this data)
    if (fabsf(B - 1.0f) < 1e-6f) return 0.0f;
    const float Bc = fmaxf(B, 1.0f);
    return __log2f(Bc + sqrtf(fmaf(Bc, Bc, -1.0f))) * 0.6931471805599453f;
}

// Kernel 2: R0 structure (stage tgt->LDS up front, sync after MFMA, f32
// epilogue) but tuned for MAX OCCUPANCY: 8 blocks/CU (32 waves/CU).
//  - minimal register liveness: tgt float4s die into LDS immediately;
//    frags loaded PER K-CHUNK (a[1]+b[4] = 20 frag VGPRs live, not 40).
//  - __launch_bounds__(256,8): VGPR cap 64, LDS 17.4KB*8 = 139KB <= 160KB.
//  - 2080 blocks / 2048 resident = 1.016 sequential rounds (was 2.03 at 4/CU):
//    the cross-round ledger (R0 102 @16w, R3 103 @16w, R6 115 @8w) says
//    waves/CU is the binding resource -> double it.
// Per-k MFMA order per acc[n] identical to R0 (k ascending) -> bit-identical.
__global__ __launch_bounds__(256, 8)
void tile_loss_kernel(const short8* __restrict__ Fr,
                      const float* __restrict__ s,
                      const float* __restrict__ tgt,
                      float* __restrict__ partials) {
    __shared__ float T[TS][TPAD];   // 17.4 KB
    __shared__ float wsum[4];

    const int t = blockIdx.x;
    int ti = (int)((sqrtf(8.0f * (float)t + 1.0f) - 1.0f) * 0.5f);
    while ((ti + 1) * (ti + 2) / 2 <= t) ti++;
    while (ti * (ti + 1) / 2 > t) ti--;
    const int tj = t - ti * (ti + 1) / 2;

    const int tid  = threadIdx.x;
    const int wave = tid >> 6;                 // 0..3 -> 16-row strip
    const int lane = tid & 63;
    const int quad = lane >> 4;
    const int l16  = lane & 15;

    const int ib0 = ti * TS;
    const int jb  = tj * TS;
    const int r0  = wave * 16 + quad * 4;

    // ---- Stage tgt tile (64x64 f32) into LDS, fully coalesced; registers
    // die immediately into ds_write (short liveness -> fits 64-VGPR cap).
    {
        const int rr = tid >> 4;
        const int cc = (tid & 15) * 4;
        #pragma unroll
        for (int p = 0; p < 4; p++) {
            const float4 tg = *(const float4*)(tgt + (size_t)(ib0 + p * 16 + rr) * N + jb + cc);
            *(float4*)&T[p * 16 + rr][cc] = tg;
        }
    }

    float sj[4];
    #pragma unroll
    for (int n = 0; n < 4; n++) sj[n] = s[jb + n * 16 + l16];
    float si[4];
    #pragma unroll
    for (int r = 0; r < 4; r++) si[r] = s[ib0 + r0 + r];

    // ---- MFMA: K=128 in 4 chunks, frags loaded per chunk (low liveness).
    f32x4 acc[4] = {};
    const int ga4 = (ti * 4 + wave) * 4;
    const int gb4 = tj * 4 * 4;
    #pragma unroll
    for (int k = 0; k < 4; k++) {
        const short8 a = Fr[(ga4 + k) * 64 + lane];
        short8 b[4];
        #pragma unroll
        for (int n = 0; n < 4; n++) b[n] = Fr[(gb4 + n * 4 + k) * 64 + lane];
        #pragma unroll
        for (int n = 0; n < 4; n++)
            acc[n] = __builtin_amdgcn_mfma_f32_16x16x32_bf16(a, b[n], acc[n], 0, 0, 0);
    }

    __syncthreads();                            // tgt tile visible in LDS

    // ---- Epilogue. C/D layout: col = l16, row = quad*4 + reg.
    float lsum = 0.0f;
    if (ti != tj) {
        #pragma unroll
        for (int r = 0; r < 4; r++)
            #pragma unroll
            for (int n = 0; n < 4; n++) {
                const float B  = fmaf(si[r], sj[n], -acc[n][r]);
                const float tv = T[r0 + r][n * 16 + l16];
                lsum += fabsf(acosh_dist(B) - tv);
            }
    } else {
        #pragma unroll
        for (int r = 0; r < 4; r++) {
            const int i = ib0 + r0 + r;
            #pragma unroll
            for (int n = 0; n < 4; n++) {
                const int j = jb + n * 16 + l16;
                if (j < i) {
                    const float B  = fmaf(si[r], sj[n], -acc[n][r]);
                    const float tv = T[r0 + r][n * 16 + l16];
                    lsum += fabsf(acosh_dist(B) - tv);
                }
            }
        }
    }

    #pragma unroll
    for (int off = 32; off > 0; off >>= 1)
        lsum += __shfl_down(lsum, off, 64);
    if (lane == 0) wsum[wave] = lsum;
    __syncthreads();
    if (tid == 0)
        partials[t] = wsum[0] + wsum[1] + wsum[2] + wsum[3];
}

// Kernel 3: reduce the 2080 block partials, scale, write the scalar loss.
__global__ __launch_bounds__(256)
void final_reduce_kernel(const float* __restrict__ partials,
                         float* __restrict__ loss) {
    __shared__ float wsum[4];
    const int tid  = threadIdx.x;
    const int wave = tid >> 6;
    const int lane = tid & 63;
    float acc = 0.0f;
    for (int i = tid; i < NBLK; i += 256) acc += partials[i];
    #pragma unroll
    for (int off = 32; off > 0; off >>= 1)
        acc += __shfl_down(acc, off, 64);
    if (lane == 0) wsum[wave] = acc;
    __syncthreads();
    if (tid == 0) {
        const float tot = wsum[0] + wsum[1] + wsum[2] + wsum[3];
        loss[0] = tot * (1.0f / ((float)N * (float)(N - 1)));
    }
}

extern "C" void kernel_launch(void* const* d_in, const int* in_sizes, int n_in,
                              void* d_out, int out_size, void* d_ws, size_t ws_size,
                              hipStream_t stream) {
    const float* O   = (const float*)d_in[0];   // [4096,128] fp32
    const float* tgt = (const float*)d_in[1];   // [4096,4096] fp32
    float* loss = (float*)d_out;                // scalar

    // ws layout: [0,1MB) frag-ordered bf16 O; [1MB,+16KB) s[]; then partials
    short8* Ofrag = (short8*)d_ws;
    float* s        = (float*)((char*)d_ws + (size_t)N * D * 2);
    float* partials = s + N;

    prep_kernel<<<NG, 256, 0, stream>>>(O, Ofrag, s);
    tile_loss_kernel<<<NBLK, 256, 0, stream>>>(Ofrag, s, tgt, partials);
    final_reduce_kernel<<<1, 256, 0, stream>>>(partials, loss);
}

// Round 8
// 120.199 us; speedup vs baseline: 1.0023x; 1.0023x over previous
//
#include <hip/hip_runtime.h>
#include <math.h>

#define N 4096
#define D 128
#define TS 64                      // output tile per 256-thread block
#define NT (N / TS)                // 64 tile rows
#define NBLK (NT * (NT + 1) / 2)   // 2080 lower-triangle tile pairs
#define NG (N / 16)                // 256 row groups of 16

typedef __attribute__((ext_vector_type(8))) short short8;  // 8 x bf16
typedef __attribute__((ext_vector_type(4))) float f32x4;

union frag_u { short8 v; unsigned int u[4]; };

__device__ __forceinline__ unsigned int pack_bf16x2(float a, float b) {
    unsigned int ua = __float_as_uint(a), ub = __float_as_uint(b);
    ua = (ua + 0x7FFFu + ((ua >> 16) & 1u)) >> 16;
    ub = (ub + 0x7FFFu + ((ub >> 16) & 1u)) >> 16;
    return ua | (ub << 16);
}

// Kernel 1: repack O into MFMA-fragment order + compute s[i]=sqrt(1+||o_i||^2).
__global__ __launch_bounds__(256)
void prep_kernel(const float* __restrict__ O,
                 short8* __restrict__ Ofrag,
                 float* __restrict__ s) {
    __shared__ float psum[16][17];
    const int g    = blockIdx.x;          // 16-row group
    const int tid  = threadIdx.x;
    const int kk   = tid >> 6;            // 0..3 (wave = K-chunk)
    const int lane = tid & 63;
    const int r16  = lane & 15;
    const int qd   = lane >> 4;           // 0..3
    const float* src = O + (size_t)(g * 16 + r16) * D + kk * 32 + qd * 8;
    const float4 v0 = *(const float4*)(src);
    const float4 v1 = *(const float4*)(src + 4);
    frag_u f;
    f.u[0] = pack_bf16x2(v0.x, v0.y);
    f.u[1] = pack_bf16x2(v0.z, v0.w);
    f.u[2] = pack_bf16x2(v1.x, v1.y);
    f.u[3] = pack_bf16x2(v1.z, v1.w);
    Ofrag[(g * 4 + kk) * 64 + lane] = f.v;
    psum[kk * 4 + qd][r16] = v0.x * v0.x + v0.y * v0.y + v0.z * v0.z + v0.w * v0.w
                           + v1.x * v1.x + v1.y * v1.y + v1.z * v1.z + v1.w * v1.w;
    __syncthreads();
    if (tid < 16) {
        float acc = 1.0f;
        #pragma unroll
        for (int x = 0; x < 16; x++) acc += psum[x][tid];
        s[g * 16 + tid] = sqrtf(acc);
    }
}

__device__ __forceinline__ float acosh_dist(float B) {
    // clamp branch |B-1|<1e-6 -> 0 (inert here: B >= ~100 for this data)
    if (fabsf(B - 1.0f) < 1e-6f) return 0.0f;
    const float Bc = fmaxf(B, 1.0f);
    return __log2f(Bc + sqrtf(fmaf(Bc, Bc, -1.0f))) * 0.6931471805599453f;
}

// Kernel 2: R1's clean structure, atomics removed. One 256-thread block per
// 64x64 tile; each wave a 16x64 strip (1x4 frags, K=128 in 4 chunks).
//  - tgt read DIRECTLY into registers at C-fragment addresses: no LDS tile,
//    no staging barrier (the only barrier is the tiny wsum reduce).
//  - Issue order: frags (older) -> tv (newer). In-order VMEM completion
//    means MFMA's register waits cover only the frags; the 16 tv loads
//    complete underneath the MFMA section.
//  - R1 measured 44 VGPR for this body -> fits 8 waves/SIMD naturally;
//    __launch_bounds__(256,8) pins it WITHOUT the R7 trap (no per-chunk
//    load serialization was needed at 44 regs).
//  - 2080 blocks / (8 blk/CU * 256 CU) = 1.016 resident rounds.
// Per-element math + reduce order identical to R0 -> bit-identical loss.
__global__ __launch_bounds__(256, 8)
void tile_loss_kernel(const short8* __restrict__ Fr,
                      const float* __restrict__ s,
                      const float* __restrict__ tgt,
                      float* __restrict__ partials) {
    __shared__ float wsum[4];

    const int t = blockIdx.x;
    int ti = (int)((sqrtf(8.0f * (float)t + 1.0f) - 1.0f) * 0.5f);
    while ((ti + 1) * (ti + 2) / 2 <= t) ti++;
    while (ti * (ti + 1) / 2 > t) ti--;
    const int tj = t - ti * (ti + 1) / 2;

    const int tid  = threadIdx.x;
    const int wave = tid >> 6;                 // 0..3 -> 16-row strip
    const int lane = tid & 63;
    const int quad = lane >> 4;
    const int l16  = lane & 15;

    const int ib0 = ti * TS;
    const int jb  = tj * TS;
    const int r0  = wave * 16 + quad * 4;

    // ---- 1) Frag loads first (oldest VMEM): a 4x, b 16x, 1 KB bursts.
    const int ga4 = (ti * 4 + wave) * 4;
    const int gb4 = tj * 4 * 4;
    short8 a[4], b[4][4];
    #pragma unroll
    for (int k = 0; k < 4; k++) a[k] = Fr[(ga4 + k) * 64 + lane];
    #pragma unroll
    for (int n = 0; n < 4; n++)
        #pragma unroll
        for (int k = 0; k < 4; k++) b[n][k] = Fr[(gb4 + n * 4 + k) * 64 + lane];

    // ---- 2) tgt at C-fragment addresses (newer than frags: completes
    // under MFMA). Each instr: 4 x 64 B aligned segments.
    float tv[4][4];
    #pragma unroll
    for (int r = 0; r < 4; r++) {
        const float* trow = tgt + (size_t)(ib0 + r0 + r) * N + jb + l16;
        #pragma unroll
        for (int n = 0; n < 4; n++) tv[r][n] = trow[n * 16];
    }

    // ---- 3) s values.
    float sj[4];
    #pragma unroll
    for (int n = 0; n < 4; n++) sj[n] = s[jb + n * 16 + l16];
    float si[4];
    #pragma unroll
    for (int r = 0; r < 4; r++) si[r] = s[ib0 + r0 + r];

    // ---- 4) MFMA: K=128 in 4 chunks (same per-acc[n] k-order as R0).
    f32x4 acc[4] = {};
    #pragma unroll
    for (int k = 0; k < 4; k++)
        #pragma unroll
        for (int n = 0; n < 4; n++)
            acc[n] = __builtin_amdgcn_mfma_f32_16x16x32_bf16(a[k], b[n][k], acc[n], 0, 0, 0);

    // ---- 5) Epilogue straight from registers (no barrier).
    float lsum = 0.0f;
    if (ti != tj) {
        #pragma unroll
        for (int r = 0; r < 4; r++)
            #pragma unroll
            for (int n = 0; n < 4; n++) {
                const float B = fmaf(si[r], sj[n], -acc[n][r]);
                lsum += fabsf(acosh_dist(B) - tv[r][n]);
            }
    } else {
        #pragma unroll
        for (int r = 0; r < 4; r++) {
            const int i = ib0 + r0 + r;
            #pragma unroll
            for (int n = 0; n < 4; n++) {
                const int j = jb + n * 16 + l16;
                if (j < i) {
                    const float B = fmaf(si[r], sj[n], -acc[n][r]);
                    lsum += fabsf(acosh_dist(B) - tv[r][n]);
                }
            }
        }
    }

    #pragma unroll
    for (int off = 32; off > 0; off >>= 1)
        lsum += __shfl_down(lsum, off, 64);
    if (lane == 0) wsum[wave] = lsum;
    __syncthreads();
    if (tid == 0)
        partials[t] = wsum[0] + wsum[1] + wsum[2] + wsum[3];
}

// Kernel 3: reduce the 2080 block partials, scale, write the scalar loss.
__global__ __launch_bounds__(256)
void final_reduce_kernel(const float* __restrict__ partials,
                         float* __restrict__ loss) {
    __shared__ float wsum[4];
    const int tid  = threadIdx.x;
    const int wave = tid >> 6;
    const int lane = tid & 63;
    float acc = 0.0f;
    for (int i = tid; i < NBLK; i += 256) acc += partials[i];
    #pragma unroll
    for (int off = 32; off > 0; off >>= 1)
        acc += __shfl_down(acc, off, 64);
    if (lane == 0) wsum[wave] = acc;
    __syncthreads();
    if (tid == 0) {
        const float tot = wsum[0] + wsum[1] + wsum[2] + wsum[3];
        loss[0] = tot * (1.0f / ((float)N * (float)(N - 1)));
    }
}

extern "C" void kernel_launch(void* const* d_in, const int* in_sizes, int n_in,
                              void* d_out, int out_size, void* d_ws, size_t ws_size,
                              hipStream_t stream) {
    const float* O   = (const float*)d_in[0];   // [4096,128] fp32
    const float* tgt = (const float*)d_in[1];   // [4096,4096] fp32
    float* loss = (float*)d_out;                // scalar

    // ws layout: [0,1MB) frag-ordered bf16 O; [1MB,+16KB) s[]; then partials
    short8* Ofrag = (short8*)d_ws;
    float* s        = (float*)((char*)d_ws + (size_t)N * D * 2);
    float* partials = s + N;

    prep_kernel<<<NG, 256, 0, stream>>>(O, Ofrag, s);
    tile_loss_kernel<<<NBLK, 256, 0, stream>>>(Ofrag, s, tgt, partials);
    final_reduce_kernel<<<1, 256, 0, stream>>>(partials, loss);
}